// Round 2
// baseline (325.171 us; speedup 1.0000x reference)
//
#include <hip/hip_runtime.h>
#include <stdint.h>

// GAT encoder, 2 layers. B=128, K=512, Fin=224, H1=64, H2=32.
// All-global-fragment design: W / Wh kept transposed ([o][k]) so every MFMA
// fragment is one 16B contiguous load; zero LDS, zero barriers in hot kernels.
// Softmax trick: att = exp(e-8)*mask / sum(exp(e-8)*mask) (exact; logits bounded ~+-7)

#define B_   128
#define K_   512
#define FIN  224
#define H1   64
#define H2   32

typedef float    f32x4 __attribute__((ext_vector_type(4)));
typedef short    s16x8 __attribute__((ext_vector_type(8)));
typedef unsigned short u16;

__device__ __forceinline__ u16 f2bf(float f){              // RNE float->bf16
  uint32_t u = __float_as_uint(f);
  u += 0x7FFFu + ((u >> 16) & 1u);
  return (u16)(u >> 16);
}
__device__ __forceinline__ float bf2f(u16 h){ return __uint_as_float(((uint32_t)h) << 16); }

// ---------------- adj -> bitmask, coalesced 16B/lane + ballot-style packing ----------------
// 2048 blocks x 256 thr x 16 iters x int4 = 8,388,608 int4 = B*K*K ints.
__global__ __launch_bounds__(256) void k_bitmask(const int* __restrict__ adj, uint32_t* __restrict__ bits){
  const int t = threadIdx.x, l = t & 63, w = t >> 6;
  const int4* ap = reinterpret_cast<const int4*>(adj) + (size_t)blockIdx.x * 4096 + t;
#pragma unroll 4
  for (int it = 0; it < 16; ++it){
    int4 v = ap[it * 256];
    uint32_t nib = (v.x != 0 ? 1u : 0u) | (v.y != 0 ? 2u : 0u) | (v.z != 0 ? 4u : 0u) | (v.w != 0 ? 8u : 0u);
    uint32_t val = nib << ((l & 7) * 4);
    val |= __shfl_xor(val, 1);
    val |= __shfl_xor(val, 2);
    val |= __shfl_xor(val, 4);                 // all 8 lanes of each group hold the word
    if ((l & 7) == 0)
      bits[(size_t)blockIdx.x * 512 + it * 32 + w * 8 + (l >> 3)] = val;
  }
}

// ---------------- W1 -> W1T bf16 [64][224], W2 -> W2T bf16 [32][64] ----------------
__global__ __launch_bounds__(256) void k_prep(const float* __restrict__ W1, const float* __restrict__ W2,
                                              u16* __restrict__ W1T, u16* __restrict__ W2T){
  int t = blockIdx.x * 256 + threadIdx.x;
  if (t < FIN * H1){ int k = t / H1, o = t % H1; W1T[o * FIN + k] = f2bf(W1[t]); }
  else { int u = t - FIN * H1; if (u < H1 * H2){ int k = u / H2, o = u % H2; W2T[o * H1 + k] = f2bf(W2[u]); } }
}

// ---------------- GEMM: Wh = A @ W (+ fused fs/fd) ----------------
// 256 thr = 4 waves; wave handles 16 rows. A-frag: row=lr, k=8g+e (global, contiguous).
// B-frag from WT[o][k] (global, L1-hot). Output written TRANSPOSED: WhT[b][o][k=i%512].
template<int KD, int NO, bool AF32>
__global__ __launch_bounds__(256) void k_gemm(const void* __restrict__ Ain, const u16* __restrict__ WT,
                                              const float* __restrict__ avec,
                                              u16* __restrict__ WhT, float* __restrict__ fs, float* __restrict__ fd){
  const int tid = threadIdx.x;
  const int wid = tid >> 6, lane = tid & 63;
  const int g = lane >> 4, lr = lane & 15;
  const size_t row0 = (size_t)blockIdx.x * 64;
  const size_t arow = row0 + 16 * wid + lr;           // this lane's A row

  f32x4 acc[NO / 16];
#pragma unroll
  for (int c = 0; c < NO/16; ++c) acc[c] = (f32x4){0.f, 0.f, 0.f, 0.f};

#pragma unroll
  for (int s = 0; s < KD / 32; ++s){
    const int k0 = s * 32 + 8 * g;
    s16x8 af;
    if (AF32){
      const float* A = (const float*)Ain;
      float4 v0 = *(const float4*)(A + arow * KD + k0);
      float4 v1 = *(const float4*)(A + arow * KD + k0 + 4);
      af[0] = (short)f2bf(v0.x); af[1] = (short)f2bf(v0.y); af[2] = (short)f2bf(v0.z); af[3] = (short)f2bf(v0.w);
      af[4] = (short)f2bf(v1.x); af[5] = (short)f2bf(v1.y); af[6] = (short)f2bf(v1.z); af[7] = (short)f2bf(v1.w);
    } else {
      af = *(const s16x8*)((const u16*)Ain + arow * KD + k0);
    }
#pragma unroll
    for (int c = 0; c < NO/16; ++c){
      const s16x8 bf = *(const s16x8*)(WT + (size_t)(16 * c + lr) * KD + k0);
      acc[c] = __builtin_amdgcn_mfma_f32_16x16x32_bf16(af, bf, acc[c], 0, 0, 0);
    }
  }

  // epilogue: lane holds D[i=row0+16wid+4g+r][o=16c+lr]. Write WhT + fused fs/fd.
  const size_t b = row0 >> 9;                          // batch (blocks never straddle)
  const int krow0 = (int)(row0 & 511) + 16 * wid + 4 * g;
  float fsp[4] = {0.f,0.f,0.f,0.f}, fdp[4] = {0.f,0.f,0.f,0.f};
#pragma unroll
  for (int c = 0; c < NO/16; ++c){
    const int o = 16 * c + lr;
    const float as = avec[o], ad = avec[NO + o];
#pragma unroll
    for (int r = 0; r < 4; ++r){
      fsp[r] += acc[c][r] * as;
      fdp[r] += acc[c][r] * ad;
      WhT[(b * NO + o) * K_ + krow0 + r] = f2bf(acc[c][r]);
    }
  }
#pragma unroll
  for (int m = 1; m < 16; m <<= 1){
#pragma unroll
    for (int r = 0; r < 4; ++r){ fsp[r] += __shfl_xor(fsp[r], m); fdp[r] += __shfl_xor(fdp[r], m); }
  }
  if (lr == 0){
#pragma unroll
    for (int r = 0; r < 4; ++r){
      size_t row = row0 + 16 * wid + 4 * g + r;
      fs[row] = fsp[r]; fd[row] = fdp[r];
    }
  }
}

// ---------------- attention: out = elu( (P @ Wh) / rowsum(P) ), barrier-free ----------------
// Operand swap: D[o][i] = WhT-frag(A) x P-frag(B). Lane's 8 computed P values ARE its
// B-fragment (col=lr -> i, k=8g+e -> j). Output [i][NO] row-major.
template<int NO, bool OUTBF>
__global__ __launch_bounds__(256) void k_attn(const u16* __restrict__ WhT, const float* __restrict__ fsv,
                                              const float* __restrict__ fdv, const uint32_t* __restrict__ bits,
                                              void* __restrict__ outp){
  const int tid = threadIdx.x;
  const int wid = tid >> 6, lane = tid & 63;
  const int g = lane >> 4, lr = lane & 15;
  const int b = blockIdx.x >> 3;
  const int i0 = (blockIdx.x & 7) * 64;
  const int irow = i0 + 16 * wid + lr;                 // this lane's P row / D col
  const float fsr = fsv[(size_t)b * K_ + irow];
  const uint32_t* brow = bits + ((size_t)b * K_ + irow) * 16;
  const float* fdb = fdv + (size_t)b * K_;
  const u16* whb = WhT + (size_t)b * NO * K_;

  f32x4 acc[NO / 16];
#pragma unroll
  for (int c = 0; c < NO/16; ++c) acc[c] = (f32x4){0.f, 0.f, 0.f, 0.f};
  float lsum = 0.f;

  for (int st = 0; st < 16; ++st){
    const int j0 = st * 32 + 8 * g;
    const uint32_t byte = (brow[st] >> (8 * g)) & 0xFFu;
    float4 fd0 = *(const float4*)(fdb + j0);
    float4 fd1 = *(const float4*)(fdb + j0 + 4);
    float pv[8] = { fd0.x, fd0.y, fd0.z, fd0.w, fd1.x, fd1.y, fd1.z, fd1.w };
    s16x8 bp;
    float lacc = 0.f;
#pragma unroll
    for (int e = 0; e < 8; ++e){
      float sc = fsr + pv[e];
      sc = fmaxf(sc, 0.2f * sc);                 // leaky_relu
      float pe = __expf(sc - 8.0f);              // shifted exp
      pe = ((byte >> e) & 1u) ? pe : 0.f;        // mask
      u16 h = f2bf(pe);
      bp[e] = (short)h;
      lacc += bf2f(h);                           // rowsum of rounded p
    }
    lsum += lacc;
#pragma unroll
    for (int c = 0; c < NO/16; ++c){
      const s16x8 aw = *(const s16x8*)(whb + (size_t)(16 * c + lr) * K_ + j0);
      acc[c] = __builtin_amdgcn_mfma_f32_16x16x32_bf16(aw, bp, acc[c], 0, 0, 0);
    }
  }

  lsum += __shfl_xor(lsum, 16);
  lsum += __shfl_xor(lsum, 32);                  // every lane: rowsum for i=irow
  const float inv = 1.0f / lsum;

  // lane holds D[o=16c+4g+r][i=irow]; write out[i][o]
#pragma unroll
  for (int c = 0; c < NO/16; ++c){
#pragma unroll
    for (int r = 0; r < 4; ++r){
      float v = acc[c][r] * inv;
      v = v > 0.f ? v : (__expf(v) - 1.0f);      // elu
      const size_t idx = ((size_t)b * K_ + irow) * NO + 16 * c + 4 * g + r;
      if (OUTBF) ((u16*)outp)[idx] = f2bf(v);
      else       ((float*)outp)[idx] = v;
    }
  }
}

extern "C" void kernel_launch(void* const* d_in, const int* in_sizes, int n_in,
                              void* d_out, int out_size, void* d_ws, size_t ws_size,
                              hipStream_t stream){
  const float* x   = (const float*)d_in[0];
  const int*   adj = (const int*)  d_in[1];
  const float* W1  = (const float*)d_in[2];
  const float* a1  = (const float*)d_in[3];
  const float* W2  = (const float*)d_in[4];
  const float* a2  = (const float*)d_in[5];
  float* out = (float*)d_out;

  char* ws = (char*)d_ws;                       // ~25.1 MB used
  u16*      WhT1 = (u16*)     (ws);             // [B][64][512] bf16  (8 MB)
  u16*      h1   = (u16*)     (ws + 8388608);   // [B*512][64] bf16   (8 MB)
  u16*      WhT2 = (u16*)     (ws + 16777216);  // [B][32][512] bf16  (4 MB)
  uint32_t* bits = (uint32_t*)(ws + 20971520);  // B*K*16 words       (4 MB)
  float*    fs1  = (float*)   (ws + 25165824);  // 256 KB each
  float*    fd1  = (float*)   (ws + 25427968);
  float*    fs2  = (float*)   (ws + 25690112);
  float*    fd2  = (float*)   (ws + 25952256);
  u16*      W1T  = (u16*)     (ws + 26214400);  // [64][224] bf16
  u16*      W2T  = (u16*)     (ws + 26243072);  // [32][64] bf16

  k_bitmask<<<dim3(2048), dim3(256), 0, stream>>>(adj, bits);
  k_prep   <<<dim3(64),   dim3(256), 0, stream>>>(W1, W2, W1T, W2T);
  k_gemm<FIN, H1, true >  <<<dim3(1024), dim3(256), 0, stream>>>((const void*)x,  W1T, a1, WhT1, fs1, fd1);
  k_attn<H1, true >       <<<dim3(1024), dim3(256), 0, stream>>>(WhT1, fs1, fd1, bits, (void*)h1);
  k_gemm<H1,  H2, false>  <<<dim3(1024), dim3(256), 0, stream>>>((const void*)h1, W2T, a2, WhT2, fs2, fd2);
  k_attn<H2, false>       <<<dim3(1024), dim3(256), 0, stream>>>(WhT2, fs2, fd2, bits, (void*)out);
}

// Round 3
// 293.861 us; speedup vs baseline: 1.1065x; 1.1065x over previous
//
#include <hip/hip_runtime.h>
#include <stdint.h>

// GAT encoder, 2 layers. B=128, K=512, Fin=224, H1=64, H2=32.
// Fragment-blocked layouts: W/Wh stored in MFMA-consumption order so every
// operand access is a contiguous 1KB wave load / 512B wave store.
// Zero LDS, zero barriers in all hot kernels.
// Softmax: att = exp(e-8)*mask / sum(exp(e-8)*mask) (exact; logits bounded ~+-7)

#define B_   128
#define K_   512
#define FIN  224
#define H1   64
#define H2   32

typedef float    f32x4 __attribute__((ext_vector_type(4)));
typedef short    s16x8 __attribute__((ext_vector_type(8)));
typedef unsigned short u16;

__device__ __forceinline__ u16 f2bf(float f){              // RNE float->bf16
  uint32_t u = __float_as_uint(f);
  u += 0x7FFFu + ((u >> 16) & 1u);
  return (u16)(u >> 16);
}
__device__ __forceinline__ float bf2f(u16 h){ return __uint_as_float(((uint32_t)h) << 16); }

// blocked fragment layout: tile (k/32, o/16) holds 512 elems; lane l's 16B chunk
// covers o = 16*(k/32-tile col base)+... : elem (o,k) -> tile*512 + (o%16 + 16*((k%32)/8))*8 + k%8
__device__ __forceinline__ int fragoff(int o, int k, int NO){
  return (((k >> 5) * (NO >> 4) + (o >> 4)) << 9) + (((o & 15) + (((k & 31) >> 3) << 4)) << 3) + (k & 7);
}

// ---------------- adj -> bits2[b][st][i] (transposed bitmask) ----------------
__global__ __launch_bounds__(256) void k_bitmask(const int* __restrict__ adj, uint32_t* __restrict__ bits2){
  const int t = threadIdx.x;
#pragma unroll 4
  for (int it = 0; it < 16; ++it){
    const size_t q = (size_t)blockIdx.x * 4096 + it * 256 + t;      // int4 index
    int4 v = reinterpret_cast<const int4*>(adj)[q];
    uint32_t nib = (v.x != 0 ? 1u : 0u) | (v.y != 0 ? 2u : 0u) | (v.z != 0 ? 4u : 0u) | (v.w != 0 ? 8u : 0u);
    uint32_t val = nib << ((t & 7) * 4);
    val |= __shfl_xor(val, 1);
    val |= __shfl_xor(val, 2);
    val |= __shfl_xor(val, 4);
    if ((t & 7) == 0){
      const size_t qw = q >> 3;                  // word id: st = qw&15, i = (qw>>4)&511, b = qw>>13
      const int st = (int)(qw & 15), i = (int)((qw >> 4) & 511), b = (int)(qw >> 13);
      bits2[((size_t)(b * 16 + st) << 9) + i] = val;
    }
  }
}

// ---------------- W1/W2 -> fragment-blocked bf16 ----------------
__global__ __launch_bounds__(256) void k_prep(const float* __restrict__ W1, const float* __restrict__ W2,
                                              u16* __restrict__ W1F, u16* __restrict__ W2F){
  int t = blockIdx.x * 256 + threadIdx.x;
  if (t < FIN * H1){ int k = t / H1, o = t % H1; W1F[fragoff(o, k, H1)] = f2bf(W1[t]); }
  else { int u = t - FIN * H1; if (u < H1 * H2){ int k = u / H2, o = u % H2; W2F[fragoff(o, k, H2)] = f2bf(W2[u]); } }
}

// ---------------- GEMM: Wh = A @ W (+ fused fs/fd), outputs WhF fragment-blocked ----------------
template<int KD, int NO, bool AF32>
__global__ __launch_bounds__(256) void k_gemm(const void* __restrict__ Ain, const u16* __restrict__ WF,
                                              const float* __restrict__ avec,
                                              u16* __restrict__ WhF, float* __restrict__ fs, float* __restrict__ fd){
  const int tid = threadIdx.x;
  const int wid = tid >> 6, lane = tid & 63;
  const int g = lane >> 4, lr = lane & 15;
  const size_t row0 = (size_t)blockIdx.x * 64;
  const size_t arow = row0 + 16 * wid + lr;            // this lane's A row

  f32x4 acc[NO / 16];
#pragma unroll
  for (int c = 0; c < NO/16; ++c) acc[c] = (f32x4){0.f, 0.f, 0.f, 0.f};

#pragma unroll
  for (int s = 0; s < KD / 32; ++s){
    const int k0 = s * 32 + 8 * g;
    s16x8 af;
    if (AF32){
      const float* A = (const float*)Ain;
      float4 v0 = *(const float4*)(A + arow * KD + k0);
      float4 v1 = *(const float4*)(A + arow * KD + k0 + 4);
      af[0] = (short)f2bf(v0.x); af[1] = (short)f2bf(v0.y); af[2] = (short)f2bf(v0.z); af[3] = (short)f2bf(v0.w);
      af[4] = (short)f2bf(v1.x); af[5] = (short)f2bf(v1.y); af[6] = (short)f2bf(v1.z); af[7] = (short)f2bf(v1.w);
    } else {
      af = *(const s16x8*)((const u16*)Ain + arow * KD + k0);
    }
#pragma unroll
    for (int c = 0; c < NO/16; ++c){
      const s16x8 bf = *(const s16x8*)(WF + ((s * (NO/16) + c) << 9) + lane * 8);
      acc[c] = __builtin_amdgcn_mfma_f32_16x16x32_bf16(af, bf, acc[c], 0, 0, 0);
    }
  }

  // epilogue: lane holds D[i=row0+16wid+4g+r][o=16c+lr]; write WhF blocked (wave-contiguous) + fs/fd
  const size_t b = row0 >> 9;
  const int krow0 = (int)(row0 & 511) + 16 * wid + 4 * g;
  float fsp[4] = {0.f,0.f,0.f,0.f}, fdp[4] = {0.f,0.f,0.f,0.f};
#pragma unroll
  for (int c = 0; c < NO/16; ++c){
    const int o = 16 * c + lr;
    const float as = avec[o], ad = avec[NO + o];
#pragma unroll
    for (int r = 0; r < 4; ++r){ fsp[r] += acc[c][r] * as; fdp[r] += acc[c][r] * ad; }
    uint2 pk;
    pk.x = (uint32_t)f2bf(acc[c][0]) | ((uint32_t)f2bf(acc[c][1]) << 16);
    pk.y = (uint32_t)f2bf(acc[c][2]) | ((uint32_t)f2bf(acc[c][3]) << 16);
    *(uint2*)(WhF + b * (NO * 512) + fragoff(o, krow0, NO)) = pk;
  }
#pragma unroll
  for (int m = 1; m < 16; m <<= 1){
#pragma unroll
    for (int r = 0; r < 4; ++r){ fsp[r] += __shfl_xor(fsp[r], m); fdp[r] += __shfl_xor(fdp[r], m); }
  }
  if (lr == 0){
#pragma unroll
    for (int r = 0; r < 4; ++r){
      size_t row = row0 + 16 * wid + 4 * g + r;
      fs[row] = fsp[r]; fd[row] = fdp[r];
    }
  }
}

// ---------------- attention: out = elu( (P @ Wh) / rowsum(P) ), barrier-free ----------------
// Operand swap: D[o][i] = WhF-frag(A) x P-frag(B); P computed in registers.
template<int NO, bool OUTBF>
__global__ __launch_bounds__(256) void k_attn(const u16* __restrict__ WhF, const float* __restrict__ fsv,
                                              const float* __restrict__ fdv, const uint32_t* __restrict__ bits2,
                                              void* __restrict__ outp){
  const int tid = threadIdx.x;
  const int wid = tid >> 6, lane = tid & 63;
  const int g = lane >> 4, lr = lane & 15;
  const int b = blockIdx.x >> 3;
  const int i0 = (blockIdx.x & 7) * 64;
  const int irow = i0 + 16 * wid + lr;                 // this lane's P row / D col
  const float fsr = fsv[(size_t)b * K_ + irow];
  const float* fdb = fdv + (size_t)b * K_;
  const uint32_t* bb = bits2 + ((size_t)b * 16 << 9);
  const u16* whb = WhF + (size_t)b * (NO * 512);

  f32x4 acc[NO / 16];
#pragma unroll
  for (int c = 0; c < NO/16; ++c) acc[c] = (f32x4){0.f, 0.f, 0.f, 0.f};
  float lsum = 0.f;

  for (int st = 0; st < 16; ++st){
    const int j0 = st * 32 + 8 * g;
    const uint32_t byte = (bb[(st << 9) + irow] >> (8 * g)) & 0xFFu;
    float4 fd0 = *(const float4*)(fdb + j0);
    float4 fd1 = *(const float4*)(fdb + j0 + 4);
    float pv[8] = { fd0.x, fd0.y, fd0.z, fd0.w, fd1.x, fd1.y, fd1.z, fd1.w };
    s16x8 bp;
    float lacc = 0.f;
#pragma unroll
    for (int e = 0; e < 8; ++e){
      float sc = fsr + pv[e];
      sc = fmaxf(sc, 0.2f * sc);                 // leaky_relu
      float pe = __expf(sc - 8.0f);              // shifted exp
      pe = ((byte >> e) & 1u) ? pe : 0.f;        // mask
      u16 h = f2bf(pe);
      bp[e] = (short)h;
      lacc += bf2f(h);                           // rowsum of rounded p
    }
    lsum += lacc;
#pragma unroll
    for (int c = 0; c < NO/16; ++c){
      const s16x8 aw = *(const s16x8*)(whb + ((st * (NO/16) + c) << 9) + lane * 8);
      acc[c] = __builtin_amdgcn_mfma_f32_16x16x32_bf16(aw, bp, acc[c], 0, 0, 0);
    }
  }

  lsum += __shfl_xor(lsum, 16);
  lsum += __shfl_xor(lsum, 32);                  // all lanes: rowsum for irow
  const float inv = 1.0f / lsum;

  // lane holds D[o=16c+4g+r][i=irow]; write out[i][o] (4 consecutive o per c)
#pragma unroll
  for (int c = 0; c < NO/16; ++c){
    float v[4];
#pragma unroll
    for (int r = 0; r < 4; ++r){
      float t = acc[c][r] * inv;
      v[r] = t > 0.f ? t : (__expf(t) - 1.0f);   // elu
    }
    const size_t base = ((size_t)b * K_ + irow) * NO + 16 * c + 4 * g;
    if (OUTBF){
      uint2 pk;
      pk.x = (uint32_t)f2bf(v[0]) | ((uint32_t)f2bf(v[1]) << 16);
      pk.y = (uint32_t)f2bf(v[2]) | ((uint32_t)f2bf(v[3]) << 16);
      *(uint2*)((u16*)outp + base) = pk;
    } else {
      *(float4*)((float*)outp + base) = (float4){v[0], v[1], v[2], v[3]};
    }
  }
}

extern "C" void kernel_launch(void* const* d_in, const int* in_sizes, int n_in,
                              void* d_out, int out_size, void* d_ws, size_t ws_size,
                              hipStream_t stream){
  const float* x   = (const float*)d_in[0];
  const int*   adj = (const int*)  d_in[1];
  const float* W1  = (const float*)d_in[2];
  const float* a1  = (const float*)d_in[3];
  const float* W2  = (const float*)d_in[4];
  const float* a2  = (const float*)d_in[5];
  float* out = (float*)d_out;

  char* ws = (char*)d_ws;                       // ~25.1 MB used
  u16*      WhF1 = (u16*)     (ws);             // [B][64*512] bf16 blocked (8 MB)
  u16*      h1   = (u16*)     (ws + 8388608);   // [B*512][64] bf16 row-major (8 MB)
  u16*      WhF2 = (u16*)     (ws + 16777216);  // [B][32*512] bf16 blocked (4 MB)
  uint32_t* bits = (uint32_t*)(ws + 20971520);  // [B][16][512] words (4 MB)
  float*    fs1  = (float*)   (ws + 25165824);
  float*    fd1  = (float*)   (ws + 25427968);
  float*    fs2  = (float*)   (ws + 25690112);
  float*    fd2  = (float*)   (ws + 25952256);
  u16*      W1F  = (u16*)     (ws + 26214400);  // 224*64 bf16 blocked
  u16*      W2F  = (u16*)     (ws + 26243072);  // 64*32 bf16 blocked

  k_bitmask<<<dim3(2048), dim3(256), 0, stream>>>(adj, bits);
  k_prep   <<<dim3(64),   dim3(256), 0, stream>>>(W1, W2, W1F, W2F);
  k_gemm<FIN, H1, true >  <<<dim3(1024), dim3(256), 0, stream>>>((const void*)x,  W1F, a1, WhF1, fs1, fd1);
  k_attn<H1, true >       <<<dim3(1024), dim3(256), 0, stream>>>(WhF1, fs1, fd1, bits, (void*)h1);
  k_gemm<H1,  H2, false>  <<<dim3(1024), dim3(256), 0, stream>>>((const void*)h1, W2F, a2, WhF2, fs2, fd2);
  k_attn<H2, false>       <<<dim3(1024), dim3(256), 0, stream>>>(WhF2, fs2, fd2, bits, (void*)out);
}